// Round 11
// baseline (1005.010 us; speedup 1.0000x reference)
//
#include <hip/hip_runtime.h>
#include <hip/hip_bf16.h>
#include <stdint.h>

// GemNet OutputBlock fused kernels for MI355X (gfx950).
// E = MLP(segment_sum(m .* (rbf@We_rbf))) @ We_out
// F = (ResMLP(ssilu(m@Wf_in)) .* (rbf@Wf_rbf)) @ Wf_out
//
// R11 changes vs R10 (force_kernel scheduling; structure frozen):
//  - #pragma unroll on the 7-stage loop: isS0/isRes/s<6 become compile-time,
//    Xr/Xw static, and the scheduler can hoist stage s+1's W-loads into
//    stage s's epilogue (W regs dead after last MFMA) -> hides L2 latency
//    at stage boundaries (the ~24% stall in R10's counters).
//  - s_setprio(1) around each rt's MFMA cluster (T5; 2 independent
//    blocks/CU = phase diversity, the regime where setprio pays).
//  - gather: rbf row as 4x float4 loads (was 16 scalar).

typedef __attribute__((ext_vector_type(8))) short bf16x8;
typedef __attribute__((ext_vector_type(4))) float f32x4;
typedef __attribute__((ext_vector_type(2))) unsigned u32x2;
typedef __attribute__((ext_vector_type(4))) unsigned u32x4;

#define INV_SQRT2 0.7071067811865476f

// ---- workspace layout (bytes) ----
#define XE_OFF     0ull
#define XE_BYTES   25600000ull                 // xE f32 [25000][256]
#define FWT_OFF    (XE_OFF + XE_BYTES)
#define FWT_BYTES  917504ull                   // FWR: 7 x [4 w][4 h][8 ks][64 lane]x16B
#define EWT0_OFF   (FWT_OFF + FWT_BYTES)
#define EWT0_BYTES 65536ull                    // [128][256] bf16
#define EWTR_OFF   (EWT0_OFF + EWT0_BYTES)
#define EWTR_BYTES 196608ull                   // 6 x [128][128] bf16
#define W2F_OFF    (EWTR_OFF + EWTR_BYTES)
#define W2F_BYTES  16384ull                    // W2FR: [4 w][4 h][64 lane]x16B
#define W2E_OFF    (W2F_OFF + W2F_BYTES)
#define W2E_BYTES  16384ull                    // (legacy, unused)
#define CNT_OFF    (W2E_OFF + W2E_BYTES)
#define CNT_BYTES  100096ull                   // counts [25000] i32 (padded)
#define OFFS_OFF   (CNT_OFF + CNT_BYTES)
#define OFFS_BYTES 100096ull                   // offsets [25001] i32
#define CURS_OFF   (OFFS_OFF + OFFS_BYTES)
#define CURS_BYTES 100096ull                   // cursors [25000] i32
#define ELIST_OFF  (CURS_OFF + CURS_BYTES)
#define ELIST_BYTES 1600000ull                 // elist [400000] i32

static __device__ __forceinline__ unsigned short f2bf(float f) {
  return __builtin_bit_cast(unsigned short, __float2bfloat16(f));
}
static __device__ __forceinline__ unsigned pack_bf16(float a, float b) {
  // two scalar RNE casts; compiler fuses to v_cvt_pk_bf16_f32 (m240 path)
  const unsigned lo = __builtin_bit_cast(unsigned short, __float2bfloat16(a));
  const unsigned hi = __builtin_bit_cast(unsigned short, __float2bfloat16(b));
  return lo | (hi << 16);
}
static __device__ __forceinline__ float bflo(unsigned p) {
  return __builtin_bit_cast(float, p << 16);
}
static __device__ __forceinline__ float bfhi(unsigned p) {
  return __builtin_bit_cast(float, p & 0xffff0000u);
}
static __device__ __forceinline__ float ssilu(float x) {
  // silu(x)/0.6 = x * sigmoid(x) * 5/3
  return 1.6666666666666667f * x * __builtin_amdgcn_rcpf(1.0f + __expf(-x));
}
static __device__ __forceinline__ void gl16(const void* g, void* l) {
  __builtin_amdgcn_global_load_lds(
      (const __attribute__((address_space(1))) void*)(unsigned long long)(uintptr_t)g,
      (__attribute__((address_space(3))) void*)(unsigned)(uintptr_t)l, 16, 0, 0);
}

// =====================================================================
// prep: weights f32 -> bf16 into frag-ready layouts (unchanged).
// =====================================================================
__global__ void prep_kernel(const float* __restrict__ We_rbf,
                            const float* __restrict__ We_in,
                            const float* __restrict__ We_res,
                            const float* __restrict__ Wf_rbf,
                            const float* __restrict__ Wf_in,
                            const float* __restrict__ Wf_res,
                            const float* __restrict__ Wf_out,
                            char* __restrict__ ws) {
  int idx = blockIdx.x * 256 + threadIdx.x;
  if (idx < 458752) {  // FWR
    int s = idx >> 16, r = idx & 65535;
    int w = r >> 14, h = (r >> 12) & 3, ks = (r >> 9) & 7, lane = (r >> 3) & 63, e = r & 7;
    int c = w * 64 + h * 16 + (lane & 15);
    int k = ks * 32 + (lane >> 4) * 8 + e;
    float v = (s == 0) ? Wf_in[k * 256 + c] : Wf_res[(s - 1) * 65536 + k * 256 + c];
    *(unsigned short*)(ws + FWT_OFF + (unsigned long long)s * 131072 + (unsigned)r * 2) = f2bf(v);
    return;
  }
  idx -= 458752;
  if (idx < 32768) {  // EWt0: [k=256][c=128] -> [c][k]
    int k = idx >> 7, c = idx & 127;
    *(unsigned short*)(ws + EWT0_OFF + c * 512 + ((k * 2) ^ ((c & 15) << 4))) = f2bf(We_in[k * 128 + c]);
    return;
  }
  idx -= 32768;
  if (idx < 98304) {  // EWtR: 6 stages [k=128][c=128] -> [c][k], rows 256B
    int s = idx >> 14, r = idx & 16383, k = r >> 7, c = r & 127;
    *(unsigned short*)(ws + EWTR_OFF + (unsigned long long)s * 32768 +
                       c * 256 + ((k * 2) ^ ((c & 15) << 4))) = f2bf(We_res[s * 16384 + k * 128 + c]);
    return;
  }
  idx -= 98304;
  if (idx < 8192) {  // W2FR
    int w = idx >> 11, h = (idx >> 9) & 3, lane = (idx >> 3) & 63, e = idx & 7;
    int c = w * 64 + h * 16 + (lane & 15);
    int k = (lane >> 4) * 8 + e;
    float v = (k < 16) ? Wf_rbf[k * 256 + c] * Wf_out[c] : 0.f;
    *(unsigned short*)(ws + W2F_OFF + (unsigned)idx * 2) = f2bf(v);
    return;
  }
}

// =====================================================================
// CSR build: count -> scan -> fill
// =====================================================================
__global__ __launch_bounds__(256) void count_kernel(
    const int* __restrict__ id_j, int* __restrict__ cnt, int nE) {
  int e = blockIdx.x * 256 + threadIdx.x;
  if (e < nE) atomicAdd(&cnt[id_j[e]], 1);
}

__global__ __launch_bounds__(1024) void scan_kernel(
    const int* __restrict__ cnt, int* __restrict__ offs,
    int* __restrict__ curs, int nA) {
  __shared__ int ps[1024];
  const int t = threadIdx.x;
  const int per = (nA + 1023) / 1024;
  const int lo = t * per, hi = min(lo + per, nA);
  int s = 0;
  for (int i = lo; i < hi; ++i) s += cnt[i];
  ps[t] = s;
  __syncthreads();
  for (int off = 1; off < 1024; off <<= 1) {
    int v = 0;
    if (t >= off) v = ps[t - off];
    __syncthreads();
    ps[t] += v;
    __syncthreads();
  }
  int run = (t == 0) ? 0 : ps[t - 1];
  for (int i = lo; i < hi; ++i) {
    offs[i] = run; curs[i] = run; run += cnt[i];
  }
  if (t == 0) offs[nA] = ps[1023];
}

__global__ __launch_bounds__(256) void fill_kernel(
    const int* __restrict__ id_j, int* __restrict__ curs,
    int* __restrict__ elist, int nE) {
  int e = blockIdx.x * 256 + threadIdx.x;
  if (e < nE) {
    int p = atomicAdd(&curs[id_j[e]], 1);
    elist[p] = e;
  }
}

// =====================================================================
// gather: xE[a][c] = sum_{e in edges(a)} m[e][c] * (rbf[e] @ We_rbf)[c]
// block = atom (25000), thread = col (256). No atomics, f32 throughout.
// =====================================================================
__global__ __launch_bounds__(256) void gather_kernel(
    const float* __restrict__ m, const float* __restrict__ rbf,
    const int* __restrict__ elist, const int* __restrict__ offs,
    const float* __restrict__ We_rbf, float* __restrict__ xE) {
  __shared__ float Wl[16][256];
  const int a = blockIdx.x;
  const int c = threadIdx.x;
#pragma unroll
  for (int k = 0; k < 16; ++k) Wl[k][c] = We_rbf[k * 256 + c];
  __syncthreads();
  const int beg = offs[a], end = offs[a + 1];
  float acc = 0.f;
  for (int j = beg; j < end; ++j) {
    const int e = elist[j];
    const float4* rpv = (const float4*)(rbf + (long long)e * 16);
    float4 r0 = rpv[0], r1 = rpv[1], r2 = rpv[2], r3 = rpv[3];
    float rw = 0.f;
    rw = fmaf(r0.x, Wl[0][c], rw);  rw = fmaf(r0.y, Wl[1][c], rw);
    rw = fmaf(r0.z, Wl[2][c], rw);  rw = fmaf(r0.w, Wl[3][c], rw);
    rw = fmaf(r1.x, Wl[4][c], rw);  rw = fmaf(r1.y, Wl[5][c], rw);
    rw = fmaf(r1.z, Wl[6][c], rw);  rw = fmaf(r1.w, Wl[7][c], rw);
    rw = fmaf(r2.x, Wl[8][c], rw);  rw = fmaf(r2.y, Wl[9][c], rw);
    rw = fmaf(r2.z, Wl[10][c], rw); rw = fmaf(r2.w, Wl[11][c], rw);
    rw = fmaf(r3.x, Wl[12][c], rw); rw = fmaf(r3.y, Wl[13][c], rw);
    rw = fmaf(r3.z, Wl[14][c], rw); rw = fmaf(r3.w, Wl[15][c], rw);
    acc = fmaf(m[(long long)e * 256 + c], rw, acc);
  }
  xE[(long long)a * 256 + c] = acc;
}

// =====================================================================
// force (column-sliced): 6250 blocks x 256 thr (4 waves); block = 64 rows;
// wave owns 64 cols. Stage loop fully unrolled; setprio around MFMA.
// =====================================================================
__global__ __launch_bounds__(256, 2) void force_kernel(
    const float* __restrict__ m, const float* __restrict__ rbf,
    const char* __restrict__ FWR, const char* __restrict__ W2FR,
    float* __restrict__ Fout, int nE) {
  __shared__ char Xbuf[2][32768];  // [64 rows][512B], swz key (row&15)<<4
  __shared__ float Fp[4][64];      // per-wave partial F
  const int tid = threadIdx.x;
  const int lane = tid & 63, q = lane >> 4, r15 = lane & 15;
  const int wid = tid >> 6;        // 0..3: cols 64*wid..+63
  const long long row0 = (long long)blockIdx.x * 64;
  const f32x4 zf = {0.f, 0.f, 0.f, 0.f};

  // ---- prologue: m -> X[0] (bf16, swizzled) ----
  {
    const int row = tid >> 2, c0 = (tid & 3) * 64;
    long long rg = row0 + row; if (rg >= nE) rg = nE - 1;
    const float* mp = m + rg * 256 + c0;
    const int key = (row & 15) << 4;
#pragma unroll
    for (int i = 0; i < 8; ++i) {
      float4 v0 = *(const float4*)(mp + i * 8);
      float4 v1 = *(const float4*)(mp + i * 8 + 4);
      u32x4 p;
      p[0] = pack_bf16(v0.x, v0.y);
      p[1] = pack_bf16(v0.z, v0.w);
      p[2] = pack_bf16(v1.x, v1.y);
      p[3] = pack_bf16(v1.z, v1.w);
      *(u32x4*)(Xbuf[0] + row * 512 + (((c0 + i * 8) * 2) ^ key)) = p;
    }
  }
  __syncthreads();

  bf16x8 W[4][8];          // wave's 64-col W-slice
  unsigned xs[4][4][2];    // residual checkpoint: [rt][h][pair of 2 bf16]

#pragma unroll
  for (int s = 0; s < 7; ++s) {
    const char* wbase = FWR + (unsigned long long)s * 131072 + wid * 32768;
#pragma unroll
    for (int h = 0; h < 4; ++h)
#pragma unroll
      for (int ks = 0; ks < 8; ++ks)
        W[h][ks] = *(const bf16x8*)(wbase + h * 8192 + ks * 1024 + lane * 16);

    const int cur = s & 1;
    const char* Xr = (const char*)Xbuf + cur * 32768;
    char* Xw = (char*)Xbuf + (cur ^ 1) * 32768;
    const bool isS0 = (s == 0);
    const bool isRes = (s >= 2) && !(s & 1);

#pragma unroll
    for (int rt = 0; rt < 4; ++rt) {
      const int row = rt * 16 + r15;
      const int key = (row & 15) << 4;
      f32x4 a[4] = {zf, zf, zf, zf};
      __builtin_amdgcn_s_setprio(1);
#pragma unroll
      for (int ks = 0; ks < 8; ++ks) {
        bf16x8 b = *(const bf16x8*)(Xr + row * 512 + ((ks * 64 + q * 16) ^ key));
        a[0] = __builtin_amdgcn_mfma_f32_16x16x32_bf16(W[0][ks], b, a[0], 0, 0, 0);
        a[1] = __builtin_amdgcn_mfma_f32_16x16x32_bf16(W[1][ks], b, a[1], 0, 0, 0);
        a[2] = __builtin_amdgcn_mfma_f32_16x16x32_bf16(W[2][ks], b, a[2], 0, 0, 0);
        a[3] = __builtin_amdgcn_mfma_f32_16x16x32_bf16(W[3][ks], b, a[3], 0, 0, 0);
      }
      __builtin_amdgcn_s_setprio(0);
#pragma unroll
      for (int h = 0; h < 4; ++h) {
        float o0 = ssilu(a[h][0]), o1 = ssilu(a[h][1]);
        float o2 = ssilu(a[h][2]), o3 = ssilu(a[h][3]);
        if (isRes) {
          const unsigned p0 = xs[rt][h][0], p1 = xs[rt][h][1];
          o0 = (bflo(p0) + o0) * INV_SQRT2;
          o1 = (bfhi(p0) + o1) * INV_SQRT2;
          o2 = (bflo(p1) + o2) * INV_SQRT2;
          o3 = (bfhi(p1) + o3) * INV_SQRT2;
        }
        const unsigned h01 = pack_bf16(o0, o1);
        const unsigned h23 = pack_bf16(o2, o3);
        if (isS0 | isRes) { xs[rt][h][0] = h01; xs[rt][h][1] = h23; }
        if (s < 6) {
          u32x2 p; p[0] = h01; p[1] = h23;
          *(u32x2*)(Xw + row * 512 + (((wid * 64 + h * 16 + q * 4) * 2) ^ key)) = p;
        }
      }
    }
    __syncthreads();
  }

  // ---- final: rw = rbf @ (Wf_rbf .* Wf_out) slice; F partial = x6 . rw ----
  bf16x8 A2[4];
#pragma unroll
  for (int h = 0; h < 4; ++h)
    A2[h] = *(const bf16x8*)(W2FR + wid * 4096 + h * 1024 + lane * 16);

  float part[4];
#pragma unroll
  for (int rt = 0; rt < 4; ++rt) {
    const int row = rt * 16 + r15;
    long long rg = row0 + row; if (rg >= nE) rg = nE - 1;
    bf16x8 br = {0, 0, 0, 0, 0, 0, 0, 0};
    if (q < 2) {  // B-frag k = q*8+e (<16); k>=16 padded zero
      const float* p = rbf + rg * 16 + q * 8;
      float4 v0 = *(const float4*)p;
      float4 v1 = *(const float4*)(p + 4);
      br[0] = (short)f2bf(v0.x); br[1] = (short)f2bf(v0.y);
      br[2] = (short)f2bf(v0.z); br[3] = (short)f2bf(v0.w);
      br[4] = (short)f2bf(v1.x); br[5] = (short)f2bf(v1.y);
      br[6] = (short)f2bf(v1.z); br[7] = (short)f2bf(v1.w);
    }
    float p = 0.f;
#pragma unroll
    for (int h = 0; h < 4; ++h) {
      f32x4 rw = __builtin_amdgcn_mfma_f32_16x16x32_bf16(A2[h], br, zf, 0, 0, 0);
      const unsigned p0 = xs[rt][h][0], p1 = xs[rt][h][1];
      p += bflo(p0) * rw[0] + bfhi(p0) * rw[1] + bflo(p1) * rw[2] + bfhi(p1) * rw[3];
    }
    part[rt] = p;
  }
#pragma unroll
  for (int rt = 0; rt < 4; ++rt) {
    part[rt] += __shfl_xor(part[rt], 16, 64);
    part[rt] += __shfl_xor(part[rt], 32, 64);
  }
  if (q == 0) {
#pragma unroll
    for (int rt = 0; rt < 4; ++rt) Fp[wid][rt * 16 + r15] = part[rt];
  }
  __syncthreads();
  if (tid < 64) {
    float sum = Fp[0][tid] + Fp[1][tid] + Fp[2][tid] + Fp[3][tid];
    const long long r = row0 + tid;
    if (r < nE) Fout[r] = sum;
  }
}

// =====================================================================
// energy MLP: xE[25000][256] -> ssilu(@We_in[256x128]) -> 3 residual(128) -> @We_out
// (unchanged)
// =====================================================================
__global__ __launch_bounds__(256) void energy_kernel(
    const float* __restrict__ xE, const char* __restrict__ EWt0,
    const char* __restrict__ EWtR, const float* __restrict__ We_out,
    float* __restrict__ Eout, int nA) {
  __shared__ char xbuf[32768];  // [128][256B], swz key (row&15)<<4
  __shared__ char wbuf[16384];
  const int tid = threadIdx.x;
  const int lane = tid & 63, q = lane >> 4, r15 = lane & 15;
  const int wid = tid >> 6, wrow = wid * 32;
  const long long row0 = (long long)blockIdx.x * 128;
  const f32x4 zf = {0.f, 0.f, 0.f, 0.f};

  bf16x8 a[2][8];
  unsigned xs[4][2][2][2];

#pragma unroll
  for (int fr = 0; fr < 2; ++fr) {
#pragma unroll
    for (int ks = 0; ks < 8; ++ks) {
      long long rg = row0 + wrow + fr * 16 + r15;
      bf16x8 t = {0, 0, 0, 0, 0, 0, 0, 0};
      if (rg < nA) {
        const float* p = xE + rg * 256 + ks * 32 + q * 8;
        float4 v0 = *(const float4*)p;
        float4 v1 = *(const float4*)(p + 4);
        t[0] = (short)f2bf(v0.x); t[1] = (short)f2bf(v0.y);
        t[2] = (short)f2bf(v0.z); t[3] = (short)f2bf(v0.w);
        t[4] = (short)f2bf(v1.x); t[5] = (short)f2bf(v1.y);
        t[6] = (short)f2bf(v1.z); t[7] = (short)f2bf(v1.w);
      }
      a[fr][ks] = t;
    }
  }

  for (int s = 0; s < 7; ++s) {
    const int K2 = (s == 0) ? 512 : 256;  // bytes per weight row
    const int wchunk = 32 * K2;
    const int nld = wchunk >> 12;         // 4 or 2 16B-loads per thread
    const char* wsrc = (s == 0) ? EWt0 : (EWtR + (unsigned long long)(s - 1) * 32768);
    const int isS0 = (s == 0);
    const int isRes = (s >= 2) && ((s & 1) == 0);
#pragma unroll
    for (int c = 0; c < 4; ++c) {
      for (int i = 0; i < nld; ++i)
        gl16(wsrc + c * wchunk + i * 4096 + tid * 16, wbuf + i * 4096 + tid * 16);
      asm volatile("s_waitcnt vmcnt(0)" ::: "memory");
      __syncthreads();

      f32x4 acc[2][2] = {{zf, zf}, {zf, zf}};
      if (s == 0) {
#pragma unroll
        for (int ks = 0; ks < 8; ++ks) {
          const int kb = ks * 64 + q * 16;
          const int ci0 = r15, ci1 = 16 + r15;
          bf16x8 b0 = *(const bf16x8*)(wbuf + ci0 * 512 + (kb ^ ((ci0 & 15) << 4)));
          bf16x8 b1 = *(const bf16x8*)(wbuf + ci1 * 512 + (kb ^ ((ci1 & 15) << 4)));
          acc[0][0] = __builtin_amdgcn_mfma_f32_16x16x32_bf16(a[0][ks], b0, acc[0][0], 0, 0, 0);
          acc[1][0] = __builtin_amdgcn_mfma_f32_16x16x32_bf16(a[1][ks], b0, acc[1][0], 0, 0, 0);
          acc[0][1] = __builtin_amdgcn_mfma_f32_16x16x32_bf16(a[0][ks], b1, acc[0][1], 0, 0, 0);
          acc[1][1] = __builtin_amdgcn_mfma_f32_16x16x32_bf16(a[1][ks], b1, acc[1][1], 0, 0, 0);
        }
      } else {
#pragma unroll
        for (int ks = 0; ks < 4; ++ks) {
          const int kb = ks * 64 + q * 16;
          const int ci0 = r15, ci1 = 16 + r15;
          bf16x8 b0 = *(const bf16x8*)(wbuf + ci0 * 256 + (kb ^ ((ci0 & 15) << 4)));
          bf16x8 b1 = *(const bf16x8*)(wbuf + ci1 * 256 + (kb ^ ((ci1 & 15) << 4)));
          acc[0][0] = __builtin_amdgcn_mfma_f32_16x16x32_bf16(a[0][ks], b0, acc[0][0], 0, 0, 0);
          acc[1][0] = __builtin_amdgcn_mfma_f32_16x16x32_bf16(a[1][ks], b0, acc[1][0], 0, 0, 0);
          acc[0][1] = __builtin_amdgcn_mfma_f32_16x16x32_bf16(a[0][ks], b1, acc[0][1], 0, 0, 0);
          acc[1][1] = __builtin_amdgcn_mfma_f32_16x16x32_bf16(a[1][ks], b1, acc[1][1], 0, 0, 0);
        }
      }
#pragma unroll
      for (int fr = 0; fr < 2; ++fr) {
#pragma unroll
        for (int fc = 0; fc < 2; ++fc) {
          float o0 = ssilu(acc[fr][fc][0]), o1 = ssilu(acc[fr][fc][1]);
          float o2 = ssilu(acc[fr][fc][2]), o3 = ssilu(acc[fr][fc][3]);
          if (isRes) {
            const unsigned p0 = xs[c][fr][fc][0], p1 = xs[c][fr][fc][1];
            o0 = (bflo(p0) + o0) * INV_SQRT2;
            o1 = (bfhi(p0) + o1) * INV_SQRT2;
            o2 = (bflo(p1) + o2) * INV_SQRT2;
            o3 = (bfhi(p1) + o3) * INV_SQRT2;
          }
          const unsigned h01 = pack_bf16(o0, o1);
          const unsigned h23 = pack_bf16(o2, o3);
          if (isS0 | isRes) {
            xs[c][fr][fc][0] = h01;
            xs[c][fr][fc][1] = h23;
          }
          if (s < 6) {
            const int colb = (c * 32 + fc * 16 + r15) * 2;
            const int rb = wrow + fr * 16 + q * 4;
            *(unsigned short*)(xbuf + (rb + 0) * 256 + (colb ^ (((rb + 0) & 15) << 4))) = (unsigned short)(h01 & 0xffff);
            *(unsigned short*)(xbuf + (rb + 1) * 256 + (colb ^ (((rb + 1) & 15) << 4))) = (unsigned short)(h01 >> 16);
            *(unsigned short*)(xbuf + (rb + 2) * 256 + (colb ^ (((rb + 2) & 15) << 4))) = (unsigned short)(h23 & 0xffff);
            *(unsigned short*)(xbuf + (rb + 3) * 256 + (colb ^ (((rb + 3) & 15) << 4))) = (unsigned short)(h23 >> 16);
          }
        }
      }
      __syncthreads();
    }
    if (s < 6) {
#pragma unroll
      for (int fr = 0; fr < 2; ++fr) {
#pragma unroll
        for (int ks = 0; ks < 4; ++ks) {
          const int row = wrow + fr * 16 + r15;
          const int kb = ks * 64 + q * 16;
          a[fr][ks] = *(const bf16x8*)(xbuf + row * 256 + (kb ^ (r15 << 4)));
        }
      }
      __syncthreads();
    }
  }

  // final: E[row] = sum_c x[row,c] * We_out[c]
  float psum[2][4] = {{0.f, 0.f, 0.f, 0.f}, {0.f, 0.f, 0.f, 0.f}};
#pragma unroll
  for (int c = 0; c < 4; ++c) {
#pragma unroll
    for (int f = 0; f < 2; ++f) {
      const int col = c * 32 + f * 16 + r15;
      const float wo = We_out[col];
#pragma unroll
      for (int fr = 0; fr < 2; ++fr) {
        const unsigned p0 = xs[c][fr][f][0], p1 = xs[c][fr][f][1];
        psum[fr][0] += bflo(p0) * wo;
        psum[fr][1] += bfhi(p0) * wo;
        psum[fr][2] += bflo(p1) * wo;
        psum[fr][3] += bfhi(p1) * wo;
      }
    }
  }
#pragma unroll
  for (int off = 1; off < 16; off <<= 1) {
#pragma unroll
    for (int fr = 0; fr < 2; ++fr) {
#pragma unroll
      for (int j = 0; j < 4; ++j) psum[fr][j] += __shfl_xor(psum[fr][j], off, 64);
    }
  }
  if (r15 == 0) {
#pragma unroll
    for (int fr = 0; fr < 2; ++fr) {
#pragma unroll
      for (int j = 0; j < 4; ++j) {
        const long long rg = row0 + wrow + fr * 16 + q * 4 + j;
        if (rg < nA) Eout[rg] = psum[fr][j];
      }
    }
  }
}

// =====================================================================
extern "C" void kernel_launch(void* const* d_in, const int* in_sizes, int n_in,
                              void* d_out, int out_size, void* d_ws, size_t ws_size,
                              hipStream_t stream) {
  const float* m      = (const float*)d_in[1];
  const float* rbf    = (const float*)d_in[2];
  const int*   id_j   = (const int*)d_in[3];
  const float* We_rbf = (const float*)d_in[4];
  const float* We_in  = (const float*)d_in[5];
  const float* We_res = (const float*)d_in[6];
  const float* We_out = (const float*)d_in[7];
  const float* Wf_rbf = (const float*)d_in[8];
  const float* Wf_in  = (const float*)d_in[9];
  const float* Wf_res = (const float*)d_in[10];
  const float* Wf_out = (const float*)d_in[11];
  const int nA = in_sizes[0] / 128;   // 25000
  const int nE = in_sizes[1] / 256;   // 400000

  char* ws = (char*)d_ws;
  float* xE   = (float*)(ws + XE_OFF);
  int*   cnt  = (int*)(ws + CNT_OFF);
  int*   offs = (int*)(ws + OFFS_OFF);
  int*   curs = (int*)(ws + CURS_OFF);
  int*   elist= (int*)(ws + ELIST_OFF);
  float* Eout = (float*)d_out;
  float* Fout = Eout + nA;

  prep_kernel<<<2368, 256, 0, stream>>>(We_rbf, We_in, We_res, Wf_rbf, Wf_in, Wf_res, Wf_out, ws);
  (void)hipMemsetAsync(cnt, 0, (size_t)nA * 4, stream);
  count_kernel<<<(nE + 255) / 256, 256, 0, stream>>>(id_j, cnt, nE);
  scan_kernel<<<1, 1024, 0, stream>>>(cnt, offs, curs, nA);
  fill_kernel<<<(nE + 255) / 256, 256, 0, stream>>>(id_j, curs, elist, nE);
  gather_kernel<<<nA, 256, 0, stream>>>(m, rbf, elist, offs, We_rbf, xE);
  energy_kernel<<<(nA + 127) / 128, 256, 0, stream>>>(xE, ws + EWT0_OFF, ws + EWTR_OFF, We_out, Eout, nA);
  force_kernel<<<(nE + 63) / 64, 256, 0, stream>>>(m, rbf, ws + FWT_OFF, ws + W2F_OFF, Fout, nE);
}

// Round 12
// 806.113 us; speedup vs baseline: 1.2467x; 1.2467x over previous
//
#include <hip/hip_runtime.h>
#include <hip/hip_bf16.h>
#include <stdint.h>

// GemNet OutputBlock fused kernels for MI355X (gfx950).
// E = MLP(segment_sum(m .* (rbf@We_rbf))) @ We_out
// F = (ResMLP(ssilu(m@Wf_in)) .* (rbf@Wf_rbf)) @ Wf_out
//
// R12 = revert R11's stage-loop unroll (it re-created scratch spills:
// WRITE 1.5MB->527MB under the (256,2) 128-arch cap; W live-range
// doubling has no register headroom). Keep setprio (T5) and gather
// float4 loads. Force kernel otherwise = R10's 627us configuration.

typedef __attribute__((ext_vector_type(8))) short bf16x8;
typedef __attribute__((ext_vector_type(4))) float f32x4;
typedef __attribute__((ext_vector_type(2))) unsigned u32x2;
typedef __attribute__((ext_vector_type(4))) unsigned u32x4;

#define INV_SQRT2 0.7071067811865476f

// ---- workspace layout (bytes) ----
#define XE_OFF     0ull
#define XE_BYTES   25600000ull                 // xE f32 [25000][256]
#define FWT_OFF    (XE_OFF + XE_BYTES)
#define FWT_BYTES  917504ull                   // FWR: 7 x [4 w][4 h][8 ks][64 lane]x16B
#define EWT0_OFF   (FWT_OFF + FWT_BYTES)
#define EWT0_BYTES 65536ull                    // [128][256] bf16
#define EWTR_OFF   (EWT0_OFF + EWT0_BYTES)
#define EWTR_BYTES 196608ull                   // 6 x [128][128] bf16
#define W2F_OFF    (EWTR_OFF + EWTR_BYTES)
#define W2F_BYTES  16384ull                    // W2FR: [4 w][4 h][64 lane]x16B
#define W2E_OFF    (W2F_OFF + W2F_BYTES)
#define W2E_BYTES  16384ull                    // (legacy, unused)
#define CNT_OFF    (W2E_OFF + W2E_BYTES)
#define CNT_BYTES  100096ull                   // counts [25000] i32 (padded)
#define OFFS_OFF   (CNT_OFF + CNT_BYTES)
#define OFFS_BYTES 100096ull                   // offsets [25001] i32
#define CURS_OFF   (OFFS_OFF + OFFS_BYTES)
#define CURS_BYTES 100096ull                   // cursors [25000] i32
#define ELIST_OFF  (CURS_OFF + CURS_BYTES)
#define ELIST_BYTES 1600000ull                 // elist [400000] i32

static __device__ __forceinline__ unsigned short f2bf(float f) {
  return __builtin_bit_cast(unsigned short, __float2bfloat16(f));
}
static __device__ __forceinline__ unsigned pack_bf16(float a, float b) {
  const unsigned lo = __builtin_bit_cast(unsigned short, __float2bfloat16(a));
  const unsigned hi = __builtin_bit_cast(unsigned short, __float2bfloat16(b));
  return lo | (hi << 16);
}
static __device__ __forceinline__ float bflo(unsigned p) {
  return __builtin_bit_cast(float, p << 16);
}
static __device__ __forceinline__ float bfhi(unsigned p) {
  return __builtin_bit_cast(float, p & 0xffff0000u);
}
static __device__ __forceinline__ float ssilu(float x) {
  // silu(x)/0.6 = x * sigmoid(x) * 5/3
  return 1.6666666666666667f * x * __builtin_amdgcn_rcpf(1.0f + __expf(-x));
}
static __device__ __forceinline__ void gl16(const void* g, void* l) {
  __builtin_amdgcn_global_load_lds(
      (const __attribute__((address_space(1))) void*)(unsigned long long)(uintptr_t)g,
      (__attribute__((address_space(3))) void*)(unsigned)(uintptr_t)l, 16, 0, 0);
}

// =====================================================================
// prep: weights f32 -> bf16 into frag-ready layouts (unchanged).
// =====================================================================
__global__ void prep_kernel(const float* __restrict__ We_rbf,
                            const float* __restrict__ We_in,
                            const float* __restrict__ We_res,
                            const float* __restrict__ Wf_rbf,
                            const float* __restrict__ Wf_in,
                            const float* __restrict__ Wf_res,
                            const float* __restrict__ Wf_out,
                            char* __restrict__ ws) {
  int idx = blockIdx.x * 256 + threadIdx.x;
  if (idx < 458752) {  // FWR
    int s = idx >> 16, r = idx & 65535;
    int w = r >> 14, h = (r >> 12) & 3, ks = (r >> 9) & 7, lane = (r >> 3) & 63, e = r & 7;
    int c = w * 64 + h * 16 + (lane & 15);
    int k = ks * 32 + (lane >> 4) * 8 + e;
    float v = (s == 0) ? Wf_in[k * 256 + c] : Wf_res[(s - 1) * 65536 + k * 256 + c];
    *(unsigned short*)(ws + FWT_OFF + (unsigned long long)s * 131072 + (unsigned)r * 2) = f2bf(v);
    return;
  }
  idx -= 458752;
  if (idx < 32768) {  // EWt0: [k=256][c=128] -> [c][k]
    int k = idx >> 7, c = idx & 127;
    *(unsigned short*)(ws + EWT0_OFF + c * 512 + ((k * 2) ^ ((c & 15) << 4))) = f2bf(We_in[k * 128 + c]);
    return;
  }
  idx -= 32768;
  if (idx < 98304) {  // EWtR: 6 stages [k=128][c=128] -> [c][k], rows 256B
    int s = idx >> 14, r = idx & 16383, k = r >> 7, c = r & 127;
    *(unsigned short*)(ws + EWTR_OFF + (unsigned long long)s * 32768 +
                       c * 256 + ((k * 2) ^ ((c & 15) << 4))) = f2bf(We_res[s * 16384 + k * 128 + c]);
    return;
  }
  idx -= 98304;
  if (idx < 8192) {  // W2FR
    int w = idx >> 11, h = (idx >> 9) & 3, lane = (idx >> 3) & 63, e = idx & 7;
    int c = w * 64 + h * 16 + (lane & 15);
    int k = (lane >> 4) * 8 + e;
    float v = (k < 16) ? Wf_rbf[k * 256 + c] * Wf_out[c] : 0.f;
    *(unsigned short*)(ws + W2F_OFF + (unsigned)idx * 2) = f2bf(v);
    return;
  }
}

// =====================================================================
// CSR build: count -> scan -> fill
// =====================================================================
__global__ __launch_bounds__(256) void count_kernel(
    const int* __restrict__ id_j, int* __restrict__ cnt, int nE) {
  int e = blockIdx.x * 256 + threadIdx.x;
  if (e < nE) atomicAdd(&cnt[id_j[e]], 1);
}

__global__ __launch_bounds__(1024) void scan_kernel(
    const int* __restrict__ cnt, int* __restrict__ offs,
    int* __restrict__ curs, int nA) {
  __shared__ int ps[1024];
  const int t = threadIdx.x;
  const int per = (nA + 1023) / 1024;
  const int lo = t * per, hi = min(lo + per, nA);
  int s = 0;
  for (int i = lo; i < hi; ++i) s += cnt[i];
  ps[t] = s;
  __syncthreads();
  for (int off = 1; off < 1024; off <<= 1) {
    int v = 0;
    if (t >= off) v = ps[t - off];
    __syncthreads();
    ps[t] += v;
    __syncthreads();
  }
  int run = (t == 0) ? 0 : ps[t - 1];
  for (int i = lo; i < hi; ++i) {
    offs[i] = run; curs[i] = run; run += cnt[i];
  }
  if (t == 0) offs[nA] = ps[1023];
}

__global__ __launch_bounds__(256) void fill_kernel(
    const int* __restrict__ id_j, int* __restrict__ curs,
    int* __restrict__ elist, int nE) {
  int e = blockIdx.x * 256 + threadIdx.x;
  if (e < nE) {
    int p = atomicAdd(&curs[id_j[e]], 1);
    elist[p] = e;
  }
}

// =====================================================================
// gather: xE[a][c] = sum_{e in edges(a)} m[e][c] * (rbf[e] @ We_rbf)[c]
// block = atom (25000), thread = col (256). No atomics, f32 throughout.
// =====================================================================
__global__ __launch_bounds__(256) void gather_kernel(
    const float* __restrict__ m, const float* __restrict__ rbf,
    const int* __restrict__ elist, const int* __restrict__ offs,
    const float* __restrict__ We_rbf, float* __restrict__ xE) {
  __shared__ float Wl[16][256];
  const int a = blockIdx.x;
  const int c = threadIdx.x;
#pragma unroll
  for (int k = 0; k < 16; ++k) Wl[k][c] = We_rbf[k * 256 + c];
  __syncthreads();
  const int beg = offs[a], end = offs[a + 1];
  float acc = 0.f;
  for (int j = beg; j < end; ++j) {
    const int e = elist[j];
    const float4* rpv = (const float4*)(rbf + (long long)e * 16);
    float4 r0 = rpv[0], r1 = rpv[1], r2 = rpv[2], r3 = rpv[3];
    float rw = 0.f;
    rw = fmaf(r0.x, Wl[0][c], rw);  rw = fmaf(r0.y, Wl[1][c], rw);
    rw = fmaf(r0.z, Wl[2][c], rw);  rw = fmaf(r0.w, Wl[3][c], rw);
    rw = fmaf(r1.x, Wl[4][c], rw);  rw = fmaf(r1.y, Wl[5][c], rw);
    rw = fmaf(r1.z, Wl[6][c], rw);  rw = fmaf(r1.w, Wl[7][c], rw);
    rw = fmaf(r2.x, Wl[8][c], rw);  rw = fmaf(r2.y, Wl[9][c], rw);
    rw = fmaf(r2.z, Wl[10][c], rw); rw = fmaf(r2.w, Wl[11][c], rw);
    rw = fmaf(r3.x, Wl[12][c], rw); rw = fmaf(r3.y, Wl[13][c], rw);
    rw = fmaf(r3.z, Wl[14][c], rw); rw = fmaf(r3.w, Wl[15][c], rw);
    acc = fmaf(m[(long long)e * 256 + c], rw, acc);
  }
  xE[(long long)a * 256 + c] = acc;
}

// =====================================================================
// force (column-sliced): 6250 blocks x 256 thr (4 waves); block = 64 rows;
// wave owns 64 cols. Rolled stage loop (R10 config) + setprio on MFMA.
// =====================================================================
__global__ __launch_bounds__(256, 2) void force_kernel(
    const float* __restrict__ m, const float* __restrict__ rbf,
    const char* __restrict__ FWR, const char* __restrict__ W2FR,
    float* __restrict__ Fout, int nE) {
  __shared__ char Xbuf[2][32768];  // [64 rows][512B], swz key (row&15)<<4
  __shared__ float Fp[4][64];      // per-wave partial F
  const int tid = threadIdx.x;
  const int lane = tid & 63, q = lane >> 4, r15 = lane & 15;
  const int wid = tid >> 6;        // 0..3: cols 64*wid..+63
  const long long row0 = (long long)blockIdx.x * 64;
  const f32x4 zf = {0.f, 0.f, 0.f, 0.f};

  // ---- prologue: m -> X[0] (bf16, swizzled) ----
  {
    const int row = tid >> 2, c0 = (tid & 3) * 64;
    long long rg = row0 + row; if (rg >= nE) rg = nE - 1;
    const float* mp = m + rg * 256 + c0;
    const int key = (row & 15) << 4;
#pragma unroll
    for (int i = 0; i < 8; ++i) {
      float4 v0 = *(const float4*)(mp + i * 8);
      float4 v1 = *(const float4*)(mp + i * 8 + 4);
      u32x4 p;
      p[0] = pack_bf16(v0.x, v0.y);
      p[1] = pack_bf16(v0.z, v0.w);
      p[2] = pack_bf16(v1.x, v1.y);
      p[3] = pack_bf16(v1.z, v1.w);
      *(u32x4*)(Xbuf[0] + row * 512 + (((c0 + i * 8) * 2) ^ key)) = p;
    }
  }
  __syncthreads();

  bf16x8 W[4][8];          // wave's 64-col W-slice
  unsigned xs[4][4][2];    // residual checkpoint: [rt][h][pair of 2 bf16]

  for (int s = 0; s < 7; ++s) {
    const char* wbase = FWR + (unsigned long long)s * 131072 + wid * 32768;
#pragma unroll
    for (int h = 0; h < 4; ++h)
#pragma unroll
      for (int ks = 0; ks < 8; ++ks)
        W[h][ks] = *(const bf16x8*)(wbase + h * 8192 + ks * 1024 + lane * 16);

    const int cur = s & 1;
    const char* Xr = (const char*)Xbuf + cur * 32768;
    char* Xw = (char*)Xbuf + (cur ^ 1) * 32768;
    const bool isS0 = (s == 0);
    const bool isRes = (s >= 2) && !(s & 1);

#pragma unroll
    for (int rt = 0; rt < 4; ++rt) {
      const int row = rt * 16 + r15;
      const int key = (row & 15) << 4;
      f32x4 a[4] = {zf, zf, zf, zf};
      __builtin_amdgcn_s_setprio(1);
#pragma unroll
      for (int ks = 0; ks < 8; ++ks) {
        bf16x8 b = *(const bf16x8*)(Xr + row * 512 + ((ks * 64 + q * 16) ^ key));
        a[0] = __builtin_amdgcn_mfma_f32_16x16x32_bf16(W[0][ks], b, a[0], 0, 0, 0);
        a[1] = __builtin_amdgcn_mfma_f32_16x16x32_bf16(W[1][ks], b, a[1], 0, 0, 0);
        a[2] = __builtin_amdgcn_mfma_f32_16x16x32_bf16(W[2][ks], b, a[2], 0, 0, 0);
        a[3] = __builtin_amdgcn_mfma_f32_16x16x32_bf16(W[3][ks], b, a[3], 0, 0, 0);
      }
      __builtin_amdgcn_s_setprio(0);
#pragma unroll
      for (int h = 0; h < 4; ++h) {
        float o0 = ssilu(a[h][0]), o1 = ssilu(a[h][1]);
        float o2 = ssilu(a[h][2]), o3 = ssilu(a[h][3]);
        if (isRes) {
          const unsigned p0 = xs[rt][h][0], p1 = xs[rt][h][1];
          o0 = (bflo(p0) + o0) * INV_SQRT2;
          o1 = (bfhi(p0) + o1) * INV_SQRT2;
          o2 = (bflo(p1) + o2) * INV_SQRT2;
          o3 = (bfhi(p1) + o3) * INV_SQRT2;
        }
        const unsigned h01 = pack_bf16(o0, o1);
        const unsigned h23 = pack_bf16(o2, o3);
        if (isS0 | isRes) { xs[rt][h][0] = h01; xs[rt][h][1] = h23; }
        if (s < 6) {
          u32x2 p; p[0] = h01; p[1] = h23;
          *(u32x2*)(Xw + row * 512 + (((wid * 64 + h * 16 + q * 4) * 2) ^ key)) = p;
        }
      }
    }
    __syncthreads();
  }

  // ---- final: rw = rbf @ (Wf_rbf .* Wf_out) slice; F partial = x6 . rw ----
  bf16x8 A2[4];
#pragma unroll
  for (int h = 0; h < 4; ++h)
    A2[h] = *(const bf16x8*)(W2FR + wid * 4096 + h * 1024 + lane * 16);

  float part[4];
#pragma unroll
  for (int rt = 0; rt < 4; ++rt) {
    const int row = rt * 16 + r15;
    long long rg = row0 + row; if (rg >= nE) rg = nE - 1;
    bf16x8 br = {0, 0, 0, 0, 0, 0, 0, 0};
    if (q < 2) {  // B-frag k = q*8+e (<16); k>=16 padded zero
      const float* p = rbf + rg * 16 + q * 8;
      float4 v0 = *(const float4*)p;
      float4 v1 = *(const float4*)(p + 4);
      br[0] = (short)f2bf(v0.x); br[1] = (short)f2bf(v0.y);
      br[2] = (short)f2bf(v0.z); br[3] = (short)f2bf(v0.w);
      br[4] = (short)f2bf(v1.x); br[5] = (short)f2bf(v1.y);
      br[6] = (short)f2bf(v1.z); br[7] = (short)f2bf(v1.w);
    }
    float p = 0.f;
#pragma unroll
    for (int h = 0; h < 4; ++h) {
      f32x4 rw = __builtin_amdgcn_mfma_f32_16x16x32_bf16(A2[h], br, zf, 0, 0, 0);
      const unsigned p0 = xs[rt][h][0], p1 = xs[rt][h][1];
      p += bflo(p0) * rw[0] + bfhi(p0) * rw[1] + bflo(p1) * rw[2] + bfhi(p1) * rw[3];
    }
    part[rt] = p;
  }
#pragma unroll
  for (int rt = 0; rt < 4; ++rt) {
    part[rt] += __shfl_xor(part[rt], 16, 64);
    part[rt] += __shfl_xor(part[rt], 32, 64);
  }
  if (q == 0) {
#pragma unroll
    for (int rt = 0; rt < 4; ++rt) Fp[wid][rt * 16 + r15] = part[rt];
  }
  __syncthreads();
  if (tid < 64) {
    float sum = Fp[0][tid] + Fp[1][tid] + Fp[2][tid] + Fp[3][tid];
    const long long r = row0 + tid;
    if (r < nE) Fout[r] = sum;
  }
}

// =====================================================================
// energy MLP: xE[25000][256] -> ssilu(@We_in[256x128]) -> 3 residual(128) -> @We_out
// (unchanged)
// =====================================================================
__global__ __launch_bounds__(256) void energy_kernel(
    const float* __restrict__ xE, const char* __restrict__ EWt0,
    const char* __restrict__ EWtR, const float* __restrict__ We_out,
    float* __restrict__ Eout, int nA) {
  __shared__ char xbuf[32768];  // [128][256B], swz key (row&15)<<4
  __shared__ char wbuf[16384];
  const int tid = threadIdx.x;
  const int lane = tid & 63, q = lane >> 4, r15 = lane & 15;
  const int wid = tid >> 6, wrow = wid * 32;
  const long long row0 = (long long)blockIdx.x * 128;
  const f32x4 zf = {0.f, 0.f, 0.f, 0.f};

  bf16x8 a[2][8];
  unsigned xs[4][2][2][2];

#pragma unroll
  for (int fr = 0; fr < 2; ++fr) {
#pragma unroll
    for (int ks = 0; ks < 8; ++ks) {
      long long rg = row0 + wrow + fr * 16 + r15;
      bf16x8 t = {0, 0, 0, 0, 0, 0, 0, 0};
      if (rg < nA) {
        const float* p = xE + rg * 256 + ks * 32 + q * 8;
        float4 v0 = *(const float4*)p;
        float4 v1 = *(const float4*)(p + 4);
        t[0] = (short)f2bf(v0.x); t[1] = (short)f2bf(v0.y);
        t[2] = (short)f2bf(v0.z); t[3] = (short)f2bf(v0.w);
        t[4] = (short)f2bf(v1.x); t[5] = (short)f2bf(v1.y);
        t[6] = (short)f2bf(v1.z); t[7] = (short)f2bf(v1.w);
      }
      a[fr][ks] = t;
    }
  }

  for (int s = 0; s < 7; ++s) {
    const int K2 = (s == 0) ? 512 : 256;  // bytes per weight row
    const int wchunk = 32 * K2;
    const int nld = wchunk >> 12;         // 4 or 2 16B-loads per thread
    const char* wsrc = (s == 0) ? EWt0 : (EWtR + (unsigned long long)(s - 1) * 32768);
    const int isS0 = (s == 0);
    const int isRes = (s >= 2) && ((s & 1) == 0);
#pragma unroll
    for (int c = 0; c < 4; ++c) {
      for (int i = 0; i < nld; ++i)
        gl16(wsrc + c * wchunk + i * 4096 + tid * 16, wbuf + i * 4096 + tid * 16);
      asm volatile("s_waitcnt vmcnt(0)" ::: "memory");
      __syncthreads();

      f32x4 acc[2][2] = {{zf, zf}, {zf, zf}};
      if (s == 0) {
#pragma unroll
        for (int ks = 0; ks < 8; ++ks) {
          const int kb = ks * 64 + q * 16;
          const int ci0 = r15, ci1 = 16 + r15;
          bf16x8 b0 = *(const bf16x8*)(wbuf + ci0 * 512 + (kb ^ ((ci0 & 15) << 4)));
          bf16x8 b1 = *(const bf16x8*)(wbuf + ci1 * 512 + (kb ^ ((ci1 & 15) << 4)));
          acc[0][0] = __builtin_amdgcn_mfma_f32_16x16x32_bf16(a[0][ks], b0, acc[0][0], 0, 0, 0);
          acc[1][0] = __builtin_amdgcn_mfma_f32_16x16x32_bf16(a[1][ks], b0, acc[1][0], 0, 0, 0);
          acc[0][1] = __builtin_amdgcn_mfma_f32_16x16x32_bf16(a[0][ks], b1, acc[0][1], 0, 0, 0);
          acc[1][1] = __builtin_amdgcn_mfma_f32_16x16x32_bf16(a[1][ks], b1, acc[1][1], 0, 0, 0);
        }
      } else {
#pragma unroll
        for (int ks = 0; ks < 4; ++ks) {
          const int kb = ks * 64 + q * 16;
          const int ci0 = r15, ci1 = 16 + r15;
          bf16x8 b0 = *(const bf16x8*)(wbuf + ci0 * 256 + (kb ^ ((ci0 & 15) << 4)));
          bf16x8 b1 = *(const bf16x8*)(wbuf + ci1 * 256 + (kb ^ ((ci1 & 15) << 4)));
          acc[0][0] = __builtin_amdgcn_mfma_f32_16x16x32_bf16(a[0][ks], b0, acc[0][0], 0, 0, 0);
          acc[1][0] = __builtin_amdgcn_mfma_f32_16x16x32_bf16(a[1][ks], b0, acc[1][0], 0, 0, 0);
          acc[0][1] = __builtin_amdgcn_mfma_f32_16x16x32_bf16(a[0][ks], b1, acc[0][1], 0, 0, 0);
          acc[1][1] = __builtin_amdgcn_mfma_f32_16x16x32_bf16(a[1][ks], b1, acc[1][1], 0, 0, 0);
        }
      }
#pragma unroll
      for (int fr = 0; fr < 2; ++fr) {
#pragma unroll
        for (int fc = 0; fc < 2; ++fc) {
          float o0 = ssilu(acc[fr][fc][0]), o1 = ssilu(acc[fr][fc][1]);
          float o2 = ssilu(acc[fr][fc][2]), o3 = ssilu(acc[fr][fc][3]);
          if (isRes) {
            const unsigned p0 = xs[c][fr][fc][0], p1 = xs[c][fr][fc][1];
            o0 = (bflo(p0) + o0) * INV_SQRT2;
            o1 = (bfhi(p0) + o1) * INV_SQRT2;
            o2 = (bflo(p1) + o2) * INV_SQRT2;
            o3 = (bfhi(p1) + o3) * INV_SQRT2;
          }
          const unsigned h01 = pack_bf16(o0, o1);
          const unsigned h23 = pack_bf16(o2, o3);
          if (isS0 | isRes) {
            xs[c][fr][fc][0] = h01;
            xs[c][fr][fc][1] = h23;
          }
          if (s < 6) {
            const int colb = (c * 32 + fc * 16 + r15) * 2;
            const int rb = wrow + fr * 16 + q * 4;
            *(unsigned short*)(xbuf + (rb + 0) * 256 + (colb ^ (((rb + 0) & 15) << 4))) = (unsigned short)(h01 & 0xffff);
            *(unsigned short*)(xbuf + (rb + 1) * 256 + (colb ^ (((rb + 1) & 15) << 4))) = (unsigned short)(h01 >> 16);
            *(unsigned short*)(xbuf + (rb + 2) * 256 + (colb ^ (((rb + 2) & 15) << 4))) = (unsigned short)(h23 & 0xffff);
            *(unsigned short*)(xbuf + (rb + 3) * 256 + (colb ^ (((rb + 3) & 15) << 4))) = (unsigned short)(h23 >> 16);
          }
        }
      }
      __syncthreads();
    }
    if (s < 6) {
#pragma unroll
      for (int fr = 0; fr < 2; ++fr) {
#pragma unroll
        for (int ks = 0; ks < 4; ++ks) {
          const int row = wrow + fr * 16 + r15;
          const int kb = ks * 64 + q * 16;
          a[fr][ks] = *(const bf16x8*)(xbuf + row * 256 + (kb ^ (r15 << 4)));
        }
      }
      __syncthreads();
    }
  }

  // final: E[row] = sum_c x[row,c] * We_out[c]
  float psum[2][4] = {{0.f, 0.f, 0.f, 0.f}, {0.f, 0.f, 0.f, 0.f}};
#pragma unroll
  for (int c = 0; c < 4; ++c) {
#pragma unroll
    for (int f = 0; f < 2; ++f) {
      const int col = c * 32 + f * 16 + r15;
      const float wo = We_out[col];
#pragma unroll
      for (int fr = 0; fr < 2; ++fr) {
        const unsigned p0 = xs[c][fr][f][0], p1 = xs[c][fr][f][1];
        psum[fr][0] += bflo(p0) * wo;
        psum[fr][1] += bfhi(p0) * wo;
        psum[fr][2] += bflo(p1) * wo;
        psum[fr][3] += bfhi(p1) * wo;
      }
    }
  }
#pragma unroll
  for (int off = 1; off < 16; off <<= 1) {
#pragma unroll
    for (int fr = 0; fr < 2; ++fr) {
#pragma unroll
      for (int j = 0; j < 4; ++j) psum[fr][j] += __shfl_xor(psum[fr][j], off, 64);
    }
  }
  if (r15 == 0) {
#pragma unroll
    for (int fr = 0; fr < 2; ++fr) {
#pragma unroll
      for (int j = 0; j < 4; ++j) {
        const long long rg = row0 + wrow + fr * 16 + q * 4 + j;
        if (rg < nA) Eout[rg] = psum[fr][j];
      }
    }
  }
}

// =====================================================================
extern "C" void kernel_launch(void* const* d_in, const int* in_sizes, int n_in,
                              void* d_out, int out_size, void* d_ws, size_t ws_size,
                              hipStream_t stream) {
  const float* m      = (const float*)d_in[1];
  const float* rbf    = (const float*)d_in[2];
  const int*   id_j   = (const int*)d_in[3];
  const float* We_rbf = (const float*)d_in[4];
  const float* We_in  = (const float*)d_in[5];
  const float* We_res = (const float*)d_in[6];
  const float* We_out = (const float*)d_in[7];
  const float* Wf_rbf = (const float*)d_in[8];
  const float* Wf_in  = (const float*)d_in[9];
  const float* Wf_res = (const float*)d_in[10];
  const float* Wf_out = (const float*)d_in[11];
  const int nA = in_sizes[0] / 128;   // 25000
  const int nE = in_sizes[1] / 256;   // 400000

  char* ws = (char*)d_ws;
  float* xE   = (float*)(ws + XE_OFF);
  int*   cnt  = (int*)(ws + CNT_OFF);
  int*   offs = (int*)(ws + OFFS_OFF);
  int*   curs = (int*)(ws + CURS_OFF);
  int*   elist= (int*)(ws + ELIST_OFF);
  float* Eout = (float*)d_out;
  float* Fout = Eout + nA;

  prep_kernel<<<2368, 256, 0, stream>>>(We_rbf, We_in, We_res, Wf_rbf, Wf_in, Wf_res, Wf_out, ws);
  (void)hipMemsetAsync(cnt, 0, (size_t)nA * 4, stream);
  count_kernel<<<(nE + 255) / 256, 256, 0, stream>>>(id_j, cnt, nE);
  scan_kernel<<<1, 1024, 0, stream>>>(cnt, offs, curs, nA);
  fill_kernel<<<(nE + 255) / 256, 256, 0, stream>>>(id_j, curs, elist, nE);
  gather_kernel<<<nA, 256, 0, stream>>>(m, rbf, elist, offs, We_rbf, xE);
  energy_kernel<<<(nA + 127) / 128, 256, 0, stream>>>(xE, ws + EWT0_OFF, ws + EWTR_OFF, We_out, Eout, nA);
  force_kernel<<<(nE + 63) / 64, 256, 0, stream>>>(m, rbf, ws + FWT_OFF, ws + W2F_OFF, Fout, nE);
}

// Round 13
// 781.434 us; speedup vs baseline: 1.2861x; 1.0316x over previous
//
#include <hip/hip_runtime.h>
#include <hip/hip_bf16.h>
#include <stdint.h>

// GemNet OutputBlock fused kernels for MI355X (gfx950).
// E = MLP(segment_sum(m .* (rbf@We_rbf))) @ We_out
// F = (ResMLP(ssilu(m@Wf_in)) .* (rbf@Wf_rbf)) @ Wf_out
//
// R13 = R12 with ONE change: pack_bf16 via inline-asm v_cvt_pk_bf16_f32
// (1 VALU inst per pair, exact RNE). R12 counters: VALUBusy 51% with ~33
// VALU inst per output value => __float2bfloat16 still lowers to the
// multi-op RNE sequence; the packed cvt is the single biggest VALU lever
// left in the (issue-bound) force epilogue.

typedef __attribute__((ext_vector_type(8))) short bf16x8;
typedef __attribute__((ext_vector_type(4))) float f32x4;
typedef __attribute__((ext_vector_type(2))) unsigned u32x2;
typedef __attribute__((ext_vector_type(4))) unsigned u32x4;

#define INV_SQRT2 0.7071067811865476f

// ---- workspace layout (bytes) ----
#define XE_OFF     0ull
#define XE_BYTES   25600000ull                 // xE f32 [25000][256]
#define FWT_OFF    (XE_OFF + XE_BYTES)
#define FWT_BYTES  917504ull                   // FWR: 7 x [4 w][4 h][8 ks][64 lane]x16B
#define EWT0_OFF   (FWT_OFF + FWT_BYTES)
#define EWT0_BYTES 65536ull                    // [128][256] bf16
#define EWTR_OFF   (EWT0_OFF + EWT0_BYTES)
#define EWTR_BYTES 196608ull                   // 6 x [128][128] bf16
#define W2F_OFF    (EWTR_OFF + EWTR_BYTES)
#define W2F_BYTES  16384ull                    // W2FR: [4 w][4 h][64 lane]x16B
#define W2E_OFF    (W2F_OFF + W2F_BYTES)
#define W2E_BYTES  16384ull                    // (legacy, unused)
#define CNT_OFF    (W2E_OFF + W2E_BYTES)
#define CNT_BYTES  100096ull                   // counts [25000] i32 (padded)
#define OFFS_OFF   (CNT_OFF + CNT_BYTES)
#define OFFS_BYTES 100096ull                   // offsets [25001] i32
#define CURS_OFF   (OFFS_OFF + OFFS_BYTES)
#define CURS_BYTES 100096ull                   // cursors [25000] i32
#define ELIST_OFF  (CURS_OFF + CURS_BYTES)
#define ELIST_BYTES 1600000ull                 // elist [400000] i32

static __device__ __forceinline__ unsigned short f2bf(float f) {
  return __builtin_bit_cast(unsigned short, __float2bfloat16(f));
}
static __device__ __forceinline__ unsigned pack_bf16(float a, float b) {
  // hardware packed RNE convert: 1 VALU inst per 2 values (T12 recipe)
  unsigned r;
  asm("v_cvt_pk_bf16_f32 %0, %1, %2" : "=v"(r) : "v"(a), "v"(b));
  return r;
}
static __device__ __forceinline__ float bflo(unsigned p) {
  return __builtin_bit_cast(float, p << 16);
}
static __device__ __forceinline__ float bfhi(unsigned p) {
  return __builtin_bit_cast(float, p & 0xffff0000u);
}
static __device__ __forceinline__ float ssilu(float x) {
  // silu(x)/0.6 = x * sigmoid(x) * 5/3
  return 1.6666666666666667f * x * __builtin_amdgcn_rcpf(1.0f + __expf(-x));
}
static __device__ __forceinline__ void gl16(const void* g, void* l) {
  __builtin_amdgcn_global_load_lds(
      (const __attribute__((address_space(1))) void*)(unsigned long long)(uintptr_t)g,
      (__attribute__((address_space(3))) void*)(unsigned)(uintptr_t)l, 16, 0, 0);
}

// =====================================================================
// prep: weights f32 -> bf16 into frag-ready layouts (unchanged).
// =====================================================================
__global__ void prep_kernel(const float* __restrict__ We_rbf,
                            const float* __restrict__ We_in,
                            const float* __restrict__ We_res,
                            const float* __restrict__ Wf_rbf,
                            const float* __restrict__ Wf_in,
                            const float* __restrict__ Wf_res,
                            const float* __restrict__ Wf_out,
                            char* __restrict__ ws) {
  int idx = blockIdx.x * 256 + threadIdx.x;
  if (idx < 458752) {  // FWR
    int s = idx >> 16, r = idx & 65535;
    int w = r >> 14, h = (r >> 12) & 3, ks = (r >> 9) & 7, lane = (r >> 3) & 63, e = r & 7;
    int c = w * 64 + h * 16 + (lane & 15);
    int k = ks * 32 + (lane >> 4) * 8 + e;
    float v = (s == 0) ? Wf_in[k * 256 + c] : Wf_res[(s - 1) * 65536 + k * 256 + c];
    *(unsigned short*)(ws + FWT_OFF + (unsigned long long)s * 131072 + (unsigned)r * 2) = f2bf(v);
    return;
  }
  idx -= 458752;
  if (idx < 32768) {  // EWt0: [k=256][c=128] -> [c][k]
    int k = idx >> 7, c = idx & 127;
    *(unsigned short*)(ws + EWT0_OFF + c * 512 + ((k * 2) ^ ((c & 15) << 4))) = f2bf(We_in[k * 128 + c]);
    return;
  }
  idx -= 32768;
  if (idx < 98304) {  // EWtR: 6 stages [k=128][c=128] -> [c][k], rows 256B
    int s = idx >> 14, r = idx & 16383, k = r >> 7, c = r & 127;
    *(unsigned short*)(ws + EWTR_OFF + (unsigned long long)s * 32768 +
                       c * 256 + ((k * 2) ^ ((c & 15) << 4))) = f2bf(We_res[s * 16384 + k * 128 + c]);
    return;
  }
  idx -= 98304;
  if (idx < 8192) {  // W2FR
    int w = idx >> 11, h = (idx >> 9) & 3, lane = (idx >> 3) & 63, e = idx & 7;
    int c = w * 64 + h * 16 + (lane & 15);
    int k = (lane >> 4) * 8 + e;
    float v = (k < 16) ? Wf_rbf[k * 256 + c] * Wf_out[c] : 0.f;
    *(unsigned short*)(ws + W2F_OFF + (unsigned)idx * 2) = f2bf(v);
    return;
  }
}

// =====================================================================
// CSR build: count -> scan -> fill
// =====================================================================
__global__ __launch_bounds__(256) void count_kernel(
    const int* __restrict__ id_j, int* __restrict__ cnt, int nE) {
  int e = blockIdx.x * 256 + threadIdx.x;
  if (e < nE) atomicAdd(&cnt[id_j[e]], 1);
}

__global__ __launch_bounds__(1024) void scan_kernel(
    const int* __restrict__ cnt, int* __restrict__ offs,
    int* __restrict__ curs, int nA) {
  __shared__ int ps[1024];
  const int t = threadIdx.x;
  const int per = (nA + 1023) / 1024;
  const int lo = t * per, hi = min(lo + per, nA);
  int s = 0;
  for (int i = lo; i < hi; ++i) s += cnt[i];
  ps[t] = s;
  __syncthreads();
  for (int off = 1; off < 1024; off <<= 1) {
    int v = 0;
    if (t >= off) v = ps[t - off];
    __syncthreads();
    ps[t] += v;
    __syncthreads();
  }
  int run = (t == 0) ? 0 : ps[t - 1];
  for (int i = lo; i < hi; ++i) {
    offs[i] = run; curs[i] = run; run += cnt[i];
  }
  if (t == 0) offs[nA] = ps[1023];
}

__global__ __launch_bounds__(256) void fill_kernel(
    const int* __restrict__ id_j, int* __restrict__ curs,
    int* __restrict__ elist, int nE) {
  int e = blockIdx.x * 256 + threadIdx.x;
  if (e < nE) {
    int p = atomicAdd(&curs[id_j[e]], 1);
    elist[p] = e;
  }
}

// =====================================================================
// gather: xE[a][c] = sum_{e in edges(a)} m[e][c] * (rbf[e] @ We_rbf)[c]
// block = atom (25000), thread = col (256). No atomics, f32 throughout.
// =====================================================================
__global__ __launch_bounds__(256) void gather_kernel(
    const float* __restrict__ m, const float* __restrict__ rbf,
    const int* __restrict__ elist, const int* __restrict__ offs,
    const float* __restrict__ We_rbf, float* __restrict__ xE) {
  __shared__ float Wl[16][256];
  const int a = blockIdx.x;
  const int c = threadIdx.x;
#pragma unroll
  for (int k = 0; k < 16; ++k) Wl[k][c] = We_rbf[k * 256 + c];
  __syncthreads();
  const int beg = offs[a], end = offs[a + 1];
  float acc = 0.f;
  for (int j = beg; j < end; ++j) {
    const int e = elist[j];
    const float4* rpv = (const float4*)(rbf + (long long)e * 16);
    float4 r0 = rpv[0], r1 = rpv[1], r2 = rpv[2], r3 = rpv[3];
    float rw = 0.f;
    rw = fmaf(r0.x, Wl[0][c], rw);  rw = fmaf(r0.y, Wl[1][c], rw);
    rw = fmaf(r0.z, Wl[2][c], rw);  rw = fmaf(r0.w, Wl[3][c], rw);
    rw = fmaf(r1.x, Wl[4][c], rw);  rw = fmaf(r1.y, Wl[5][c], rw);
    rw = fmaf(r1.z, Wl[6][c], rw);  rw = fmaf(r1.w, Wl[7][c], rw);
    rw = fmaf(r2.x, Wl[8][c], rw);  rw = fmaf(r2.y, Wl[9][c], rw);
    rw = fmaf(r2.z, Wl[10][c], rw); rw = fmaf(r2.w, Wl[11][c], rw);
    rw = fmaf(r3.x, Wl[12][c], rw); rw = fmaf(r3.y, Wl[13][c], rw);
    rw = fmaf(r3.z, Wl[14][c], rw); rw = fmaf(r3.w, Wl[15][c], rw);
    acc = fmaf(m[(long long)e * 256 + c], rw, acc);
  }
  xE[(long long)a * 256 + c] = acc;
}

// =====================================================================
// force (column-sliced): 6250 blocks x 256 thr (4 waves); block = 64 rows;
// wave owns 64 cols. Rolled stage loop + setprio; asm cvt_pk epilogue.
// =====================================================================
__global__ __launch_bounds__(256, 2) void force_kernel(
    const float* __restrict__ m, const float* __restrict__ rbf,
    const char* __restrict__ FWR, const char* __restrict__ W2FR,
    float* __restrict__ Fout, int nE) {
  __shared__ char Xbuf[2][32768];  // [64 rows][512B], swz key (row&15)<<4
  __shared__ float Fp[4][64];      // per-wave partial F
  const int tid = threadIdx.x;
  const int lane = tid & 63, q = lane >> 4, r15 = lane & 15;
  const int wid = tid >> 6;        // 0..3: cols 64*wid..+63
  const long long row0 = (long long)blockIdx.x * 64;
  const f32x4 zf = {0.f, 0.f, 0.f, 0.f};

  // ---- prologue: m -> X[0] (bf16, swizzled) ----
  {
    const int row = tid >> 2, c0 = (tid & 3) * 64;
    long long rg = row0 + row; if (rg >= nE) rg = nE - 1;
    const float* mp = m + rg * 256 + c0;
    const int key = (row & 15) << 4;
#pragma unroll
    for (int i = 0; i < 8; ++i) {
      float4 v0 = *(const float4*)(mp + i * 8);
      float4 v1 = *(const float4*)(mp + i * 8 + 4);
      u32x4 p;
      p[0] = pack_bf16(v0.x, v0.y);
      p[1] = pack_bf16(v0.z, v0.w);
      p[2] = pack_bf16(v1.x, v1.y);
      p[3] = pack_bf16(v1.z, v1.w);
      *(u32x4*)(Xbuf[0] + row * 512 + (((c0 + i * 8) * 2) ^ key)) = p;
    }
  }
  __syncthreads();

  bf16x8 W[4][8];          // wave's 64-col W-slice
  unsigned xs[4][4][2];    // residual checkpoint: [rt][h][pair of 2 bf16]

  for (int s = 0; s < 7; ++s) {
    const char* wbase = FWR + (unsigned long long)s * 131072 + wid * 32768;
#pragma unroll
    for (int h = 0; h < 4; ++h)
#pragma unroll
      for (int ks = 0; ks < 8; ++ks)
        W[h][ks] = *(const bf16x8*)(wbase + h * 8192 + ks * 1024 + lane * 16);

    const int cur = s & 1;
    const char* Xr = (const char*)Xbuf + cur * 32768;
    char* Xw = (char*)Xbuf + (cur ^ 1) * 32768;
    const bool isS0 = (s == 0);
    const bool isRes = (s >= 2) && !(s & 1);

#pragma unroll
    for (int rt = 0; rt < 4; ++rt) {
      const int row = rt * 16 + r15;
      const int key = (row & 15) << 4;
      f32x4 a[4] = {zf, zf, zf, zf};
      __builtin_amdgcn_s_setprio(1);
#pragma unroll
      for (int ks = 0; ks < 8; ++ks) {
        bf16x8 b = *(const bf16x8*)(Xr + row * 512 + ((ks * 64 + q * 16) ^ key));
        a[0] = __builtin_amdgcn_mfma_f32_16x16x32_bf16(W[0][ks], b, a[0], 0, 0, 0);
        a[1] = __builtin_amdgcn_mfma_f32_16x16x32_bf16(W[1][ks], b, a[1], 0, 0, 0);
        a[2] = __builtin_amdgcn_mfma_f32_16x16x32_bf16(W[2][ks], b, a[2], 0, 0, 0);
        a[3] = __builtin_amdgcn_mfma_f32_16x16x32_bf16(W[3][ks], b, a[3], 0, 0, 0);
      }
      __builtin_amdgcn_s_setprio(0);
#pragma unroll
      for (int h = 0; h < 4; ++h) {
        float o0 = ssilu(a[h][0]), o1 = ssilu(a[h][1]);
        float o2 = ssilu(a[h][2]), o3 = ssilu(a[h][3]);
        if (isRes) {
          const unsigned p0 = xs[rt][h][0], p1 = xs[rt][h][1];
          o0 = (bflo(p0) + o0) * INV_SQRT2;
          o1 = (bfhi(p0) + o1) * INV_SQRT2;
          o2 = (bflo(p1) + o2) * INV_SQRT2;
          o3 = (bfhi(p1) + o3) * INV_SQRT2;
        }
        const unsigned h01 = pack_bf16(o0, o1);
        const unsigned h23 = pack_bf16(o2, o3);
        if (isS0 | isRes) { xs[rt][h][0] = h01; xs[rt][h][1] = h23; }
        if (s < 6) {
          u32x2 p; p[0] = h01; p[1] = h23;
          *(u32x2*)(Xw + row * 512 + (((wid * 64 + h * 16 + q * 4) * 2) ^ key)) = p;
        }
      }
    }
    __syncthreads();
  }

  // ---- final: rw = rbf @ (Wf_rbf .* Wf_out) slice; F partial = x6 . rw ----
  bf16x8 A2[4];
#pragma unroll
  for (int h = 0; h < 4; ++h)
    A2[h] = *(const bf16x8*)(W2FR + wid * 4096 + h * 1024 + lane * 16);

  float part[4];
#pragma unroll
  for (int rt = 0; rt < 4; ++rt) {
    const int row = rt * 16 + r15;
    long long rg = row0 + row; if (rg >= nE) rg = nE - 1;
    bf16x8 br = {0, 0, 0, 0, 0, 0, 0, 0};
    if (q < 2) {  // B-frag k = q*8+e (<16); k>=16 padded zero
      const float* p = rbf + rg * 16 + q * 8;
      float4 v0 = *(const float4*)p;
      float4 v1 = *(const float4*)(p + 4);
      br[0] = (short)f2bf(v0.x); br[1] = (short)f2bf(v0.y);
      br[2] = (short)f2bf(v0.z); br[3] = (short)f2bf(v0.w);
      br[4] = (short)f2bf(v1.x); br[5] = (short)f2bf(v1.y);
      br[6] = (short)f2bf(v1.z); br[7] = (short)f2bf(v1.w);
    }
    float p = 0.f;
#pragma unroll
    for (int h = 0; h < 4; ++h) {
      f32x4 rw = __builtin_amdgcn_mfma_f32_16x16x32_bf16(A2[h], br, zf, 0, 0, 0);
      const unsigned p0 = xs[rt][h][0], p1 = xs[rt][h][1];
      p += bflo(p0) * rw[0] + bfhi(p0) * rw[1] + bflo(p1) * rw[2] + bfhi(p1) * rw[3];
    }
    part[rt] = p;
  }
#pragma unroll
  for (int rt = 0; rt < 4; ++rt) {
    part[rt] += __shfl_xor(part[rt], 16, 64);
    part[rt] += __shfl_xor(part[rt], 32, 64);
  }
  if (q == 0) {
#pragma unroll
    for (int rt = 0; rt < 4; ++rt) Fp[wid][rt * 16 + r15] = part[rt];
  }
  __syncthreads();
  if (tid < 64) {
    float sum = Fp[0][tid] + Fp[1][tid] + Fp[2][tid] + Fp[3][tid];
    const long long r = row0 + tid;
    if (r < nE) Fout[r] = sum;
  }
}

// =====================================================================
// energy MLP: xE[25000][256] -> ssilu(@We_in[256x128]) -> 3 residual(128) -> @We_out
// (asm cvt_pk epilogue; otherwise unchanged)
// =====================================================================
__global__ __launch_bounds__(256) void energy_kernel(
    const float* __restrict__ xE, const char* __restrict__ EWt0,
    const char* __restrict__ EWtR, const float* __restrict__ We_out,
    float* __restrict__ Eout, int nA) {
  __shared__ char xbuf[32768];  // [128][256B], swz key (row&15)<<4
  __shared__ char wbuf[16384];
  const int tid = threadIdx.x;
  const int lane = tid & 63, q = lane >> 4, r15 = lane & 15;
  const int wid = tid >> 6, wrow = wid * 32;
  const long long row0 = (long long)blockIdx.x * 128;
  const f32x4 zf = {0.f, 0.f, 0.f, 0.f};

  bf16x8 a[2][8];
  unsigned xs[4][2][2][2];

#pragma unroll
  for (int fr = 0; fr < 2; ++fr) {
#pragma unroll
    for (int ks = 0; ks < 8; ++ks) {
      long long rg = row0 + wrow + fr * 16 + r15;
      bf16x8 t = {0, 0, 0, 0, 0, 0, 0, 0};
      if (rg < nA) {
        const float* p = xE + rg * 256 + ks * 32 + q * 8;
        float4 v0 = *(const float4*)p;
        float4 v1 = *(const float4*)(p + 4);
        t[0] = (short)f2bf(v0.x); t[1] = (short)f2bf(v0.y);
        t[2] = (short)f2bf(v0.z); t[3] = (short)f2bf(v0.w);
        t[4] = (short)f2bf(v1.x); t[5] = (short)f2bf(v1.y);
        t[6] = (short)f2bf(v1.z); t[7] = (short)f2bf(v1.w);
      }
      a[fr][ks] = t;
    }
  }

  for (int s = 0; s < 7; ++s) {
    const int K2 = (s == 0) ? 512 : 256;  // bytes per weight row
    const int wchunk = 32 * K2;
    const int nld = wchunk >> 12;         // 4 or 2 16B-loads per thread
    const char* wsrc = (s == 0) ? EWt0 : (EWtR + (unsigned long long)(s - 1) * 32768);
    const int isS0 = (s == 0);
    const int isRes = (s >= 2) && ((s & 1) == 0);
#pragma unroll
    for (int c = 0; c < 4; ++c) {
      for (int i = 0; i < nld; ++i)
        gl16(wsrc + c * wchunk + i * 4096 + tid * 16, wbuf + i * 4096 + tid * 16);
      asm volatile("s_waitcnt vmcnt(0)" ::: "memory");
      __syncthreads();

      f32x4 acc[2][2] = {{zf, zf}, {zf, zf}};
      if (s == 0) {
#pragma unroll
        for (int ks = 0; ks < 8; ++ks) {
          const int kb = ks * 64 + q * 16;
          const int ci0 = r15, ci1 = 16 + r15;
          bf16x8 b0 = *(const bf16x8*)(wbuf + ci0 * 512 + (kb ^ ((ci0 & 15) << 4)));
          bf16x8 b1 = *(const bf16x8*)(wbuf + ci1 * 512 + (kb ^ ((ci1 & 15) << 4)));
          acc[0][0] = __builtin_amdgcn_mfma_f32_16x16x32_bf16(a[0][ks], b0, acc[0][0], 0, 0, 0);
          acc[1][0] = __builtin_amdgcn_mfma_f32_16x16x32_bf16(a[1][ks], b0, acc[1][0], 0, 0, 0);
          acc[0][1] = __builtin_amdgcn_mfma_f32_16x16x32_bf16(a[0][ks], b1, acc[0][1], 0, 0, 0);
          acc[1][1] = __builtin_amdgcn_mfma_f32_16x16x32_bf16(a[1][ks], b1, acc[1][1], 0, 0, 0);
        }
      } else {
#pragma unroll
        for (int ks = 0; ks < 4; ++ks) {
          const int kb = ks * 64 + q * 16;
          const int ci0 = r15, ci1 = 16 + r15;
          bf16x8 b0 = *(const bf16x8*)(wbuf + ci0 * 256 + (kb ^ ((ci0 & 15) << 4)));
          bf16x8 b1 = *(const bf16x8*)(wbuf + ci1 * 256 + (kb ^ ((ci1 & 15) << 4)));
          acc[0][0] = __builtin_amdgcn_mfma_f32_16x16x32_bf16(a[0][ks], b0, acc[0][0], 0, 0, 0);
          acc[1][0] = __builtin_amdgcn_mfma_f32_16x16x32_bf16(a[1][ks], b0, acc[1][0], 0, 0, 0);
          acc[0][1] = __builtin_amdgcn_mfma_f32_16x16x32_bf16(a[0][ks], b1, acc[0][1], 0, 0, 0);
          acc[1][1] = __builtin_amdgcn_mfma_f32_16x16x32_bf16(a[1][ks], b1, acc[1][1], 0, 0, 0);
        }
      }
#pragma unroll
      for (int fr = 0; fr < 2; ++fr) {
#pragma unroll
        for (int fc = 0; fc < 2; ++fc) {
          float o0 = ssilu(acc[fr][fc][0]), o1 = ssilu(acc[fr][fc][1]);
          float o2 = ssilu(acc[fr][fc][2]), o3 = ssilu(acc[fr][fc][3]);
          if (isRes) {
            const unsigned p0 = xs[c][fr][fc][0], p1 = xs[c][fr][fc][1];
            o0 = (bflo(p0) + o0) * INV_SQRT2;
            o1 = (bfhi(p0) + o1) * INV_SQRT2;
            o2 = (bflo(p1) + o2) * INV_SQRT2;
            o3 = (bfhi(p1) + o3) * INV_SQRT2;
          }
          const unsigned h01 = pack_bf16(o0, o1);
          const unsigned h23 = pack_bf16(o2, o3);
          if (isS0 | isRes) {
            xs[c][fr][fc][0] = h01;
            xs[c][fr][fc][1] = h23;
          }
          if (s < 6) {
            const int colb = (c * 32 + fc * 16 + r15) * 2;
            const int rb = wrow + fr * 16 + q * 4;
            *(unsigned short*)(xbuf + (rb + 0) * 256 + (colb ^ (((rb + 0) & 15) << 4))) = (unsigned short)(h01 & 0xffff);
            *(unsigned short*)(xbuf + (rb + 1) * 256 + (colb ^ (((rb + 1) & 15) << 4))) = (unsigned short)(h01 >> 16);
            *(unsigned short*)(xbuf + (rb + 2) * 256 + (colb ^ (((rb + 2) & 15) << 4))) = (unsigned short)(h23 & 0xffff);
            *(unsigned short*)(xbuf + (rb + 3) * 256 + (colb ^ (((rb + 3) & 15) << 4))) = (unsigned short)(h23 >> 16);
          }
        }
      }
      __syncthreads();
    }
    if (s < 6) {
#pragma unroll
      for (int fr = 0; fr < 2; ++fr) {
#pragma unroll
        for (int ks = 0; ks < 4; ++ks) {
          const int row = wrow + fr * 16 + r15;
          const int kb = ks * 64 + q * 16;
          a[fr][ks] = *(const bf16x8*)(xbuf + row * 256 + (kb ^ (r15 << 4)));
        }
      }
      __syncthreads();
    }
  }

  // final: E[row] = sum_c x[row,c] * We_out[c]
  float psum[2][4] = {{0.f, 0.f, 0.f, 0.f}, {0.f, 0.f, 0.f, 0.f}};
#pragma unroll
  for (int c = 0; c < 4; ++c) {
#pragma unroll
    for (int f = 0; f < 2; ++f) {
      const int col = c * 32 + f * 16 + r15;
      const float wo = We_out[col];
#pragma unroll
      for (int fr = 0; fr < 2; ++fr) {
        const unsigned p0 = xs[c][fr][f][0], p1 = xs[c][fr][f][1];
        psum[fr][0] += bflo(p0) * wo;
        psum[fr][1] += bfhi(p0) * wo;
        psum[fr][2] += bflo(p1) * wo;
        psum[fr][3] += bfhi(p1) * wo;
      }
    }
  }
#pragma unroll
  for (int off = 1; off < 16; off <<= 1) {
#pragma unroll
    for (int fr = 0; fr < 2; ++fr) {
#pragma unroll
      for (int j = 0; j < 4; ++j) psum[fr][j] += __shfl_xor(psum[fr][j], off, 64);
    }
  }
  if (r15 == 0) {
#pragma unroll
    for (int fr = 0; fr < 2; ++fr) {
#pragma unroll
      for (int j = 0; j < 4; ++j) {
        const long long rg = row0 + wrow + fr * 16 + q * 4 + j;
        if (rg < nA) Eout[rg] = psum[fr][j];
      }
    }
  }
}

// =====================================================================
extern "C" void kernel_launch(void* const* d_in, const int* in_sizes, int n_in,
                              void* d_out, int out_size, void* d_ws, size_t ws_size,
                              hipStream_t stream) {
  const float* m      = (const float*)d_in[1];
  const float* rbf    = (const float*)d_in[2];
  const int*   id_j   = (const int*)d_in[3];
  const float* We_rbf = (const float*)d_in[4];
  const float* We_in  = (const float*)d_in[5];
  const float* We_res = (const float*)d_in[6];
  const float* We_out = (const float*)d_in[7];
  const float* Wf_rbf = (const float*)d_in[8];
  const float* Wf_in  = (const float*)d_in[9];
  const float* Wf_res = (const float*)d_in[10];
  const float* Wf_out = (const float*)d_in[11];
  const int nA = in_sizes[0] / 128;   // 25000
  const int nE = in_sizes[1] / 256;   // 400000

  char* ws = (char*)d_ws;
  float* xE   = (float*)(ws + XE_OFF);
  int*   cnt  = (int*)(ws + CNT_OFF);
  int*   offs = (int*)(ws + OFFS_OFF);
  int*   curs = (int*)(ws + CURS_OFF);
  int*   elist= (int*)(ws + ELIST_OFF);
  float* Eout = (float*)d_out;
  float* Fout = Eout + nA;

  prep_kernel<<<2368, 256, 0, stream>>>(We_rbf, We_in, We_res, Wf_rbf, Wf_in, Wf_res, Wf_out, ws);
  (void)hipMemsetAsync(cnt, 0, (size_t)nA * 4, stream);
  count_kernel<<<(nE + 255) / 256, 256, 0, stream>>>(id_j, cnt, nE);
  scan_kernel<<<1, 1024, 0, stream>>>(cnt, offs, curs, nA);
  fill_kernel<<<(nE + 255) / 256, 256, 0, stream>>>(id_j, curs, elist, nE);
  gather_kernel<<<nA, 256, 0, stream>>>(m, rbf, elist, offs, We_rbf, xE);
  energy_kernel<<<(nA + 127) / 128, 256, 0, stream>>>(xE, ws + EWT0_OFF, ws + EWTR_OFF, We_out, Eout, nA);
  force_kernel<<<(nE + 63) / 64, 256, 0, stream>>>(m, rbf, ws + FWT_OFF, ws + W2F_OFF, Fout, nE);
}